// Round 3
// baseline (287.128 us; speedup 1.0000x reference)
//
#include <hip/hip_runtime.h>
#include <hip/hip_bf16.h>
#include <stdint.h>

#define BATCH 32
#define SRCN 1024
#define SEQL 128
#define CTXN 5
#define DMOD 512

typedef __attribute__((ext_vector_type(8))) short short8;
typedef __attribute__((ext_vector_type(4))) float floatx4;

typedef __attribute__((address_space(3))) void lds_t;
typedef __attribute__((address_space(1))) void glb_t;

__device__ __forceinline__ void gload_lds16(const void* g, void* l) {
    __builtin_amdgcn_global_load_lds((const glb_t*)g, (lds_t*)l, 16, 0, 0);
}

__device__ __forceinline__ ushort f2b(float f) {
    __hip_bfloat16 h = __float2bfloat16(f);
    return *reinterpret_cast<ushort*>(&h);
}

// ---------------------------------------------------------------------------
// Convert F_emb fp32 -> bf16 table (GEMM2 B-gather + xet gather read this;
// 64 MB fp32 -> 32 MB bf16, stays L3-resident)
// ---------------------------------------------------------------------------
__global__ __launch_bounds__(256) void k_cvtF(
    const float* __restrict__ F, ushort* __restrict__ Fb)
{
    const int n8 = 32000 * DMOD / 8;
    const int stride = gridDim.x * 256;
    for (int i = blockIdx.x * 256 + threadIdx.x; i < n8; i += stride) {
        const float4 a = *(const float4*)(F + (size_t)i * 8);
        const float4 b = *(const float4*)(F + (size_t)i * 8 + 4);
        union { ushort u[8]; uint4 v; } o;
        o.u[0] = f2b(a.x); o.u[1] = f2b(a.y); o.u[2] = f2b(a.z); o.u[3] = f2b(a.w);
        o.u[4] = f2b(b.x); o.u[5] = f2b(b.y); o.u[6] = f2b(b.z); o.u[7] = f2b(b.w);
        *(uint4*)(Fb + (size_t)i * 8) = o.v;
    }
}

// ---------------------------------------------------------------------------
// Gather+convert yce[4096][2560] bf16 (5 G_emb rows per (b,s))
// ---------------------------------------------------------------------------
__global__ __launch_bounds__(256) void k_yce(
    const int* __restrict__ yc, const float* __restrict__ G,
    ushort* __restrict__ yce)
{
    const int r = blockIdx.x;            // 0..4095 = b*128+s
    const int b = r >> 7, s = r & 127;
    const int tid = threadIdx.x;
    for (int i = tid; i < 640; i += 256) {
        const int c = i >> 7;            // context slot 0..4
        const int tok = yc[b * (SEQL * CTXN) + s * CTXN + c];
        const float4 v = *(const float4*)(G + (size_t)tok * DMOD + (i & 127) * 4);
        ushort4 o;
        o.x = f2b(v.x); o.y = f2b(v.y); o.z = f2b(v.z); o.w = f2b(v.w);
        *(ushort4*)(yce + (size_t)r * 2560 + i * 4) = o;
    }
}

// ---------------------------------------------------------------------------
// Transpose+convert P_w [2560][512] f32 -> pwt [512][2560] bf16
// ---------------------------------------------------------------------------
__global__ __launch_bounds__(256) void k_pwt(
    const float* __restrict__ Pw, ushort* __restrict__ Pwt)
{
    __shared__ float t[64][68];
    const int k0 = blockIdx.x * 64, n0 = blockIdx.y * 64;
    const int tid = threadIdx.x;
    #pragma unroll
    for (int it = 0; it < 4; ++it) {
        const int c = tid + it * 256;
        const int kr = c >> 4, c4 = c & 15;
        const float4 v = *(const float4*)(Pw + (size_t)(k0 + kr) * DMOD + n0 + c4 * 4);
        t[kr][c4 * 4 + 0] = v.x; t[kr][c4 * 4 + 1] = v.y;
        t[kr][c4 * 4 + 2] = v.z; t[kr][c4 * 4 + 3] = v.w;
    }
    __syncthreads();
    #pragma unroll
    for (int it = 0; it < 2; ++it) {
        const int c = tid + it * 256;
        const int n = c >> 3, seg = c & 7;
        ushort4 o0, o1;
        o0.x = f2b(t[seg * 8 + 0][n]); o0.y = f2b(t[seg * 8 + 1][n]);
        o0.z = f2b(t[seg * 8 + 2][n]); o0.w = f2b(t[seg * 8 + 3][n]);
        o1.x = f2b(t[seg * 8 + 4][n]); o1.y = f2b(t[seg * 8 + 5][n]);
        o1.z = f2b(t[seg * 8 + 6][n]); o1.w = f2b(t[seg * 8 + 7][n]);
        ushort* dst = Pwt + (size_t)(n0 + n) * 2560 + k0 + seg * 8;
        *(ushort4*)dst = o0; *(ushort4*)(dst + 4) = o1;
    }
}

// ---------------------------------------------------------------------------
// GEMM1 (split-K=2): part[ks][4096][512] = yce[.,ksK:] @ pwt[.,ksK:]^T
// 64x64 tile, BK=64, 4 waves each 32x32. fp32 partials.
// ---------------------------------------------------------------------------
__global__ __launch_bounds__(256) void k_gemm_py(
    const ushort* __restrict__ yce, const ushort* __restrict__ pwt,
    float* __restrict__ part)
{
    __shared__ ushort As[8 * 512];   // [kc][m][8]
    __shared__ ushort Bs[8 * 512];   // [kc][n][8]
    const int tid = threadIdx.x;
    const int w = tid >> 6, lane = tid & 63;
    const int l15 = lane & 15, q = lane >> 4;
    const int wm = w >> 1, wn = w & 1;
    const int m0 = blockIdx.y * 64, n0 = blockIdx.x * 64;
    const int ks = blockIdx.z;

    const ushort* Arow = yce + (size_t)(m0 + lane) * 2560 + ks * 1280;
    const ushort* Brow = pwt + (size_t)(n0 + lane) * 2560 + ks * 1280;

    floatx4 acc[2][2];
    #pragma unroll
    for (int mi = 0; mi < 2; ++mi)
        #pragma unroll
        for (int ni = 0; ni < 2; ++ni)
            acc[mi][ni] = (floatx4){0.f, 0.f, 0.f, 0.f};

    for (int kk = 0; kk < 1280; kk += 64) {
        __syncthreads();
        #pragma unroll
        for (int i = 0; i < 2; ++i) {
            const int kc = w * 2 + i;
            gload_lds16(Arow + kk + kc * 8, (void*)(As + kc * 512));
            gload_lds16(Brow + kk + kc * 8, (void*)(Bs + kc * 512));
        }
        __syncthreads();
        #pragma unroll
        for (int s2 = 0; s2 < 2; ++s2) {
            const int kc = s2 * 4 + q;
            short8 af[2], bf[2];
            af[0] = *(const short8*)(As + kc * 512 + (wm * 32 + l15) * 8);
            af[1] = *(const short8*)(As + kc * 512 + (wm * 32 + 16 + l15) * 8);
            bf[0] = *(const short8*)(Bs + kc * 512 + (wn * 32 + l15) * 8);
            bf[1] = *(const short8*)(Bs + kc * 512 + (wn * 32 + 16 + l15) * 8);
            #pragma unroll
            for (int mi = 0; mi < 2; ++mi)
                #pragma unroll
                for (int ni = 0; ni < 2; ++ni)
                    acc[mi][ni] = __builtin_amdgcn_mfma_f32_16x16x32_bf16(
                        af[mi], bf[ni], acc[mi][ni], 0, 0, 0);
        }
    }

    float* dst = part + (size_t)ks * (4096LL * DMOD);
    #pragma unroll
    for (int ni = 0; ni < 2; ++ni) {
        const int col = n0 + wn * 32 + ni * 16 + l15;
        #pragma unroll
        for (int mi = 0; mi < 2; ++mi) {
            const int row0 = m0 + wm * 32 + mi * 16 + q * 4;
            #pragma unroll
            for (int r = 0; r < 4; ++r)
                dst[(size_t)(row0 + r) * DMOD + col] = acc[mi][ni][r];
        }
    }
}

// ---------------------------------------------------------------------------
// Reduce split-K partials + bias -> py bf16 [4096][512]
// ---------------------------------------------------------------------------
__global__ __launch_bounds__(256) void k_red(
    const float* __restrict__ part, const float* __restrict__ Pb,
    ushort* __restrict__ py)
{
    const int i = blockIdx.x * 256 + threadIdx.x;   // vec4 id, 524288 total
    const float4 a = *(const float4*)(part + (size_t)i * 4);
    const float4 b = *(const float4*)(part + 4096LL * DMOD + (size_t)i * 4);
    const float4 bias = *(const float4*)(Pb + ((i * 4) & 511));
    ushort4 o;
    o.x = f2b(a.x + b.x + bias.x);
    o.y = f2b(a.y + b.y + bias.y);
    o.z = f2b(a.z + b.z + bias.z);
    o.w = f2b(a.w + b.w + bias.w);
    *(ushort4*)(py + (size_t)i * 4) = o;
}

// ---------------------------------------------------------------------------
// Gathered transpose: xet[b][d][x] = Fb[x_tok[b,x]][d]  (bf16)
// ---------------------------------------------------------------------------
__global__ __launch_bounds__(256) void k_xetg(
    const int* __restrict__ x, const ushort* __restrict__ Fb,
    ushort* __restrict__ xet)
{
    __shared__ ushort t[64][72];
    const int z = blockIdx.z;
    const int x0 = blockIdx.x * 64, d0 = blockIdx.y * 64;
    ushort* out = xet + (size_t)z * DMOD * SRCN;
    const int tid = threadIdx.x;
    #pragma unroll
    for (int it = 0; it < 2; ++it) {
        const int c = tid + it * 256;
        const int xr = c >> 3, seg = c & 7;
        const int tok = x[z * SRCN + x0 + xr];
        const uint4 v = *(const uint4*)(Fb + (size_t)tok * DMOD + d0 + seg * 8);
        *(uint4*)&t[xr][seg * 8] = v;
    }
    __syncthreads();
    #pragma unroll
    for (int it = 0; it < 2; ++it) {
        const int c = tid + it * 256;
        const int d = c >> 3, seg = c & 7;
        ushort4 o0, o1;
        o0.x = t[seg * 8 + 0][d]; o0.y = t[seg * 8 + 1][d];
        o0.z = t[seg * 8 + 2][d]; o0.w = t[seg * 8 + 3][d];
        o1.x = t[seg * 8 + 4][d]; o1.y = t[seg * 8 + 5][d];
        o1.z = t[seg * 8 + 6][d]; o1.w = t[seg * 8 + 7][d];
        ushort* dst = out + (size_t)(d0 + d) * SRCN + x0 + seg * 8;
        *(ushort4*)dst = o0; *(ushort4*)(dst + 4) = o1;
    }
}

// ---------------------------------------------------------------------------
// GEMM2: scores[b][128][1024] = py_b @ xe_b^T  (K=512), B gathered from Fb.
// Mask fused; fp32 out into `a` region.
// ---------------------------------------------------------------------------
__global__ __launch_bounds__(256) void k_gemm_sc(
    const ushort* __restrict__ py, const int* __restrict__ x,
    const ushort* __restrict__ Fb, float* __restrict__ a_out)
{
    __shared__ ushort As[8 * 512];
    __shared__ ushort Bs[8 * 512];
    const int tid = threadIdx.x;
    const int w = tid >> 6, lane = tid & 63;
    const int l15 = lane & 15, q = lane >> 4;
    const int wm = w >> 1, wn = w & 1;
    const int z = blockIdx.z;
    const int m0 = blockIdx.y * 64, n0 = blockIdx.x * 64;

    const ushort* Arow = py + (size_t)(z * SEQL + m0 + lane) * DMOD;
    const int tok = x[z * SRCN + n0 + lane];
    const ushort* Brow = Fb + (size_t)tok * DMOD;

    floatx4 acc[2][2];
    #pragma unroll
    for (int mi = 0; mi < 2; ++mi)
        #pragma unroll
        for (int ni = 0; ni < 2; ++ni)
            acc[mi][ni] = (floatx4){0.f, 0.f, 0.f, 0.f};

    for (int kk = 0; kk < DMOD; kk += 64) {
        __syncthreads();
        #pragma unroll
        for (int i = 0; i < 2; ++i) {
            const int kc = w * 2 + i;
            gload_lds16(Arow + kk + kc * 8, (void*)(As + kc * 512));
            gload_lds16(Brow + kk + kc * 8, (void*)(Bs + kc * 512));
        }
        __syncthreads();
        #pragma unroll
        for (int s2 = 0; s2 < 2; ++s2) {
            const int kc = s2 * 4 + q;
            short8 af[2], bf[2];
            af[0] = *(const short8*)(As + kc * 512 + (wm * 32 + l15) * 8);
            af[1] = *(const short8*)(As + kc * 512 + (wm * 32 + 16 + l15) * 8);
            bf[0] = *(const short8*)(Bs + kc * 512 + (wn * 32 + l15) * 8);
            bf[1] = *(const short8*)(Bs + kc * 512 + (wn * 32 + 16 + l15) * 8);
            #pragma unroll
            for (int mi = 0; mi < 2; ++mi)
                #pragma unroll
                for (int ni = 0; ni < 2; ++ni)
                    acc[mi][ni] = __builtin_amdgcn_mfma_f32_16x16x32_bf16(
                        af[mi], bf[ni], acc[mi][ni], 0, 0, 0);
        }
    }

    #pragma unroll
    for (int ni = 0; ni < 2; ++ni) {
        const int col = n0 + wn * 32 + ni * 16 + l15;
        const float msk = (x[z * SRCN + col] == 0) ? -1e9f : 0.0f;
        #pragma unroll
        for (int mi = 0; mi < 2; ++mi) {
            const int row0 = m0 + wm * 32 + mi * 16 + q * 4;
            #pragma unroll
            for (int r = 0; r < 4; ++r)
                a_out[((size_t)z * SEQL + row0 + r) * SRCN + col] = acc[mi][ni][r] + msk;
        }
    }
}

// ---------------------------------------------------------------------------
// Mask already applied; row softmax over 1024; fp32 in place + bf16 copy
// ---------------------------------------------------------------------------
__global__ __launch_bounds__(256) void k_softmax(
    float* __restrict__ a, ushort* __restrict__ abf)
{
    const int row = blockIdx.x;          // b*128+s
    float* p = a + (size_t)row * SRCN;
    ushort* pb = abf + (size_t)row * SRCN;
    const int tid = threadIdx.x;
    const int wave = tid >> 6, lane = tid & 63;

    float4 v = *(const float4*)(p + tid * 4);

    float mx = fmaxf(fmaxf(v.x, v.y), fmaxf(v.z, v.w));
    #pragma unroll
    for (int off = 32; off > 0; off >>= 1)
        mx = fmaxf(mx, __shfl_down(mx, off, 64));
    __shared__ float redm[4];
    if (lane == 0) redm[wave] = mx;
    __syncthreads();
    mx = fmaxf(fmaxf(redm[0], redm[1]), fmaxf(redm[2], redm[3]));

    const float e0 = __expf(v.x - mx);
    const float e1 = __expf(v.y - mx);
    const float e2 = __expf(v.z - mx);
    const float e3 = __expf(v.w - mx);

    float sm = e0 + e1 + e2 + e3;
    #pragma unroll
    for (int off = 32; off > 0; off >>= 1)
        sm += __shfl_down(sm, off, 64);
    __shared__ float reds[4];
    if (lane == 0) reds[wave] = sm;
    __syncthreads();
    sm = reds[0] + reds[1] + reds[2] + reds[3];

    const float inv = 1.0f / sm;
    float4 o;
    o.x = e0 * inv; o.y = e1 * inv; o.z = e2 * inv; o.w = e3 * inv;
    *(float4*)(p + tid * 4) = o;
    ushort4 ob;
    ob.x = f2b(o.x); ob.y = f2b(o.y); ob.z = f2b(o.z); ob.w = f2b(o.w);
    *(ushort4*)(pb + tid * 4) = ob;
}

// ---------------------------------------------------------------------------
// GEMM3: out[b][128][512] = abf_b @ xet_b^T  (K=1024), fp32 out
// ---------------------------------------------------------------------------
__global__ __launch_bounds__(256) void k_gemm_out(
    const ushort* __restrict__ abf, const ushort* __restrict__ xet,
    float* __restrict__ outp)
{
    __shared__ ushort As[8 * 512];
    __shared__ ushort Bs[8 * 512];
    const int tid = threadIdx.x;
    const int w = tid >> 6, lane = tid & 63;
    const int l15 = lane & 15, q = lane >> 4;
    const int wm = w >> 1, wn = w & 1;
    const int z = blockIdx.z;
    const int m0 = blockIdx.y * 64, n0 = blockIdx.x * 64;

    const ushort* Arow = abf + (size_t)(z * SEQL + m0 + lane) * SRCN;
    const ushort* Brow = xet + (size_t)z * DMOD * SRCN + (size_t)(n0 + lane) * SRCN;

    floatx4 acc[2][2];
    #pragma unroll
    for (int mi = 0; mi < 2; ++mi)
        #pragma unroll
        for (int ni = 0; ni < 2; ++ni)
            acc[mi][ni] = (floatx4){0.f, 0.f, 0.f, 0.f};

    for (int kk = 0; kk < SRCN; kk += 64) {
        __syncthreads();
        #pragma unroll
        for (int i = 0; i < 2; ++i) {
            const int kc = w * 2 + i;
            gload_lds16(Arow + kk + kc * 8, (void*)(As + kc * 512));
            gload_lds16(Brow + kk + kc * 8, (void*)(Bs + kc * 512));
        }
        __syncthreads();
        #pragma unroll
        for (int s2 = 0; s2 < 2; ++s2) {
            const int kc = s2 * 4 + q;
            short8 af[2], bf[2];
            af[0] = *(const short8*)(As + kc * 512 + (wm * 32 + l15) * 8);
            af[1] = *(const short8*)(As + kc * 512 + (wm * 32 + 16 + l15) * 8);
            bf[0] = *(const short8*)(Bs + kc * 512 + (wn * 32 + l15) * 8);
            bf[1] = *(const short8*)(Bs + kc * 512 + (wn * 32 + 16 + l15) * 8);
            #pragma unroll
            for (int mi = 0; mi < 2; ++mi)
                #pragma unroll
                for (int ni = 0; ni < 2; ++ni)
                    acc[mi][ni] = __builtin_amdgcn_mfma_f32_16x16x32_bf16(
                        af[mi], bf[ni], acc[mi][ni], 0, 0, 0);
        }
    }

    #pragma unroll
    for (int ni = 0; ni < 2; ++ni) {
        const int col = n0 + wn * 32 + ni * 16 + l15;
        #pragma unroll
        for (int mi = 0; mi < 2; ++mi) {
            const int row0 = m0 + wm * 32 + mi * 16 + q * 4;
            #pragma unroll
            for (int r = 0; r < 4; ++r)
                outp[((size_t)z * SEQL + row0 + r) * DMOD + col] = acc[mi][ni][r];
        }
    }
}

// ---------------------------------------------------------------------------
extern "C" void kernel_launch(void* const* d_in, const int* in_sizes, int n_in,
                              void* d_out, int out_size, void* d_ws, size_t ws_size,
                              hipStream_t stream)
{
    const int*   x    = (const int*)d_in[0];    // [32,1024]
    const int*   yc   = (const int*)d_in[1];    // [32,640]
    const float* Femb = (const float*)d_in[2];  // [32000,512]
    const float* Gemb = (const float*)d_in[3];  // [32000,512]
    const float* Pw   = (const float*)d_in[4];  // [2560,512]
    const float* Pb   = (const float*)d_in[5];  // [512]

    float* out_p = (float*)d_out;                         // [32,128,512]
    float* a_p   = out_p + (size_t)BATCH * SEQL * DMOD;   // [32,128,1024]

    // Workspace layout (91.5 MB total, with lifetime-based aliasing):
    //   Fb   [0,        32768000)  bf16 F table       (live: cvtF .. gemm_sc)
    //   yce  [32768000, 53739520)  bf16 yce           (live: yce .. gemm_py)
    //   abf  aliases yce region    (live: softmax .. gemm_out)
    //   pwt  [53739520, 56360960)  (live: pwt .. gemm_py)
    //   part [56360960, 73138176)  2x fp32 partials   (live: gemm_py .. red)
    //   xet  [53739520, 87293952)  overwrites pwt+part (live: xetg .. gemm_out)
    //   py   [87293952, 91488256)  bf16               (live: red .. gemm_sc)
    char* ws = (char*)d_ws;
    ushort* Fb   = (ushort*)(ws);
    ushort* yce  = (ushort*)(ws + 32768000);
    ushort* abf  = (ushort*)(ws + 32768000);
    ushort* pwt  = (ushort*)(ws + 53739520);
    float*  part = (float*) (ws + 56360960);
    ushort* xet  = (ushort*)(ws + 53739520);
    ushort* py   = (ushort*)(ws + 87293952);

    dim3 blk(256);
    k_cvtF<<<dim3(1024), blk, 0, stream>>>(Femb, Fb);
    k_yce<<<dim3(4096), blk, 0, stream>>>(yc, Gemb, yce);
    k_pwt<<<dim3(40, 8), blk, 0, stream>>>(Pw, pwt);

    // GEMM1 split-K=2: 1024 blocks (4/CU)
    k_gemm_py<<<dim3(8, 64, 2), blk, 0, stream>>>(yce, pwt, part);
    k_red<<<dim3(2048), blk, 0, stream>>>(part, Pb, py);

    // xet gather-transpose (after k_red: overwrites pwt/part region)
    k_xetg<<<dim3(16, 8, 32), blk, 0, stream>>>(x, Fb, xet);

    // GEMM2: 1024 blocks (4/CU), B gathered from Fb, mask fused
    k_gemm_sc<<<dim3(16, 2, BATCH), blk, 0, stream>>>(py, x, Fb, a_p);
    k_softmax<<<dim3(4096), blk, 0, stream>>>(a_p, abf);
    // GEMM3: 512 blocks (2/CU)
    k_gemm_out<<<dim3(8, 2, BATCH), blk, 0, stream>>>(abf, xet, out_p);
}

// Round 4
// 277.804 us; speedup vs baseline: 1.0336x; 1.0336x over previous
//
#include <hip/hip_runtime.h>
#include <hip/hip_bf16.h>
#include <stdint.h>

#define BATCH 32
#define SRCN 1024
#define SEQL 128
#define CTXN 5
#define DMOD 512

typedef __attribute__((ext_vector_type(8))) short short8;
typedef __attribute__((ext_vector_type(4))) float floatx4;

typedef __attribute__((address_space(3))) void lds_t;
typedef __attribute__((address_space(1))) void glb_t;

__device__ __forceinline__ void gload_lds16(const void* g, void* l) {
    __builtin_amdgcn_global_load_lds((const glb_t*)g, (lds_t*)l, 16, 0, 0);
}

__device__ __forceinline__ ushort f2b(float f) {
    __hip_bfloat16 h = __float2bfloat16(f);
    return *reinterpret_cast<ushort*>(&h);
}

// ---------------------------------------------------------------------------
// Gather+convert yce[4096][2560] bf16 (5 G_emb rows per (b,s))
// ---------------------------------------------------------------------------
__global__ __launch_bounds__(256) void k_yce(
    const int* __restrict__ yc, const float* __restrict__ G,
    ushort* __restrict__ yce)
{
    const int r = blockIdx.x;            // 0..4095 = b*128+s
    const int b = r >> 7, s = r & 127;
    const int tid = threadIdx.x;
    for (int i = tid; i < 640; i += 256) {
        const int c = i >> 7;            // context slot 0..4
        const int tok = yc[b * (SEQL * CTXN) + s * CTXN + c];
        const float4 v = *(const float4*)(G + (size_t)tok * DMOD + (i & 127) * 4);
        ushort4 o;
        o.x = f2b(v.x); o.y = f2b(v.y); o.z = f2b(v.z); o.w = f2b(v.w);
        *(ushort4*)(yce + (size_t)r * 2560 + i * 4) = o;
    }
}

// ---------------------------------------------------------------------------
// Transpose+convert P_w [2560][512] f32 -> pwt [512][2560] bf16
// ---------------------------------------------------------------------------
__global__ __launch_bounds__(256) void k_pwt(
    const float* __restrict__ Pw, ushort* __restrict__ Pwt)
{
    __shared__ float t[64][68];
    const int k0 = blockIdx.x * 64, n0 = blockIdx.y * 64;
    const int tid = threadIdx.x;
    #pragma unroll
    for (int it = 0; it < 4; ++it) {
        const int c = tid + it * 256;
        const int kr = c >> 4, c4 = c & 15;
        const float4 v = *(const float4*)(Pw + (size_t)(k0 + kr) * DMOD + n0 + c4 * 4);
        t[kr][c4 * 4 + 0] = v.x; t[kr][c4 * 4 + 1] = v.y;
        t[kr][c4 * 4 + 2] = v.z; t[kr][c4 * 4 + 3] = v.w;
    }
    __syncthreads();
    #pragma unroll
    for (int it = 0; it < 2; ++it) {
        const int c = tid + it * 256;
        const int n = c >> 3, seg = c & 7;
        ushort4 o0, o1;
        o0.x = f2b(t[seg * 8 + 0][n]); o0.y = f2b(t[seg * 8 + 1][n]);
        o0.z = f2b(t[seg * 8 + 2][n]); o0.w = f2b(t[seg * 8 + 3][n]);
        o1.x = f2b(t[seg * 8 + 4][n]); o1.y = f2b(t[seg * 8 + 5][n]);
        o1.z = f2b(t[seg * 8 + 6][n]); o1.w = f2b(t[seg * 8 + 7][n]);
        ushort* dst = Pwt + (size_t)(n0 + n) * 2560 + k0 + seg * 8;
        *(ushort4*)dst = o0; *(ushort4*)(dst + 4) = o1;
    }
}

// ---------------------------------------------------------------------------
// GEMM1 (split-K=4, XCD-swizzled): part[ks] = yce[., ks*640:] @ pwt^T slice
// 64x64 tile, BK=64. Swizzle: blocks sharing an m-panel have equal id%8.
// ---------------------------------------------------------------------------
__global__ __launch_bounds__(256) void k_gemm_py(
    const ushort* __restrict__ yce, const ushort* __restrict__ pwt,
    float* __restrict__ part)
{
    __shared__ ushort As[8 * 512];   // [kc][m][8]
    __shared__ ushort Bs[8 * 512];   // [kc][n][8]
    const int f = blockIdx.x;        // 0..2047
    const int n  = (f >> 3) & 7;
    const int m  = (f & 7) | (((f >> 6) & 7) << 3);
    const int ks = f >> 9;
    const int tid = threadIdx.x;
    const int w = tid >> 6, lane = tid & 63;
    const int l15 = lane & 15, q = lane >> 4;
    const int wm = w >> 1, wn = w & 1;
    const int m0 = m * 64, n0 = n * 64, koff = ks * 640;

    const ushort* Arow = yce + (size_t)(m0 + lane) * 2560 + koff;
    const ushort* Brow = pwt + (size_t)(n0 + lane) * 2560 + koff;

    floatx4 acc[2][2];
    #pragma unroll
    for (int mi = 0; mi < 2; ++mi)
        #pragma unroll
        for (int ni = 0; ni < 2; ++ni)
            acc[mi][ni] = (floatx4){0.f, 0.f, 0.f, 0.f};

    for (int kk = 0; kk < 640; kk += 64) {
        __syncthreads();
        #pragma unroll
        for (int i = 0; i < 2; ++i) {
            const int cc = w * 2 + i;
            gload_lds16(Arow + kk + cc * 8, (void*)(As + cc * 512));
            gload_lds16(Brow + kk + cc * 8, (void*)(Bs + cc * 512));
        }
        __syncthreads();
        #pragma unroll
        for (int s2 = 0; s2 < 2; ++s2) {
            const int kc = s2 * 4 + q;
            short8 af[2], bf[2];
            af[0] = *(const short8*)(As + kc * 512 + (wm * 32 + l15) * 8);
            af[1] = *(const short8*)(As + kc * 512 + (wm * 32 + 16 + l15) * 8);
            bf[0] = *(const short8*)(Bs + kc * 512 + (wn * 32 + l15) * 8);
            bf[1] = *(const short8*)(Bs + kc * 512 + (wn * 32 + 16 + l15) * 8);
            #pragma unroll
            for (int mi = 0; mi < 2; ++mi)
                #pragma unroll
                for (int ni = 0; ni < 2; ++ni)
                    acc[mi][ni] = __builtin_amdgcn_mfma_f32_16x16x32_bf16(
                        af[mi], bf[ni], acc[mi][ni], 0, 0, 0);
        }
    }

    float* dst = part + (size_t)ks * (4096LL * DMOD);
    #pragma unroll
    for (int ni = 0; ni < 2; ++ni) {
        const int col = n0 + wn * 32 + ni * 16 + l15;
        #pragma unroll
        for (int mi = 0; mi < 2; ++mi) {
            const int row0 = m0 + wm * 32 + mi * 16 + q * 4;
            #pragma unroll
            for (int r = 0; r < 4; ++r)
                dst[(size_t)(row0 + r) * DMOD + col] = acc[mi][ni][r];
        }
    }
}

// ---------------------------------------------------------------------------
// Reduce 4 split-K partials + bias -> py bf16 [4096][512]
// ---------------------------------------------------------------------------
__global__ __launch_bounds__(256) void k_red4(
    const float* __restrict__ part, const float* __restrict__ Pb,
    ushort* __restrict__ py)
{
    const long long SL = 4096LL * DMOD;
    const int i = blockIdx.x * 256 + threadIdx.x;   // vec4 id, 524288 total
    const float4 a = *(const float4*)(part + (size_t)i * 4);
    const float4 b = *(const float4*)(part + SL + (size_t)i * 4);
    const float4 c = *(const float4*)(part + 2 * SL + (size_t)i * 4);
    const float4 d = *(const float4*)(part + 3 * SL + (size_t)i * 4);
    const float4 bias = *(const float4*)(Pb + ((i * 4) & 511));
    ushort4 o;
    o.x = f2b(a.x + b.x + c.x + d.x + bias.x);
    o.y = f2b(a.y + b.y + c.y + d.y + bias.y);
    o.z = f2b(a.z + b.z + c.z + d.z + bias.z);
    o.w = f2b(a.w + b.w + c.w + d.w + bias.w);
    *(ushort4*)(py + (size_t)i * 4) = o;
}

// ---------------------------------------------------------------------------
// Gather F fp32 rows once -> xe[b][x][d] bf16 AND xet[b][d][x] bf16.
// Replaces full-vocab convert + separate gathered transpose.
// ---------------------------------------------------------------------------
__global__ __launch_bounds__(256) void k_xe2(
    const int* __restrict__ x, const float* __restrict__ F,
    ushort* __restrict__ xe, ushort* __restrict__ xet)
{
    __shared__ ushort t[64][72];
    const int z = blockIdx.z;
    const int x0 = blockIdx.x * 64, d0 = blockIdx.y * 64;
    const int tid = threadIdx.x;
    #pragma unroll
    for (int it = 0; it < 4; ++it) {
        const int c = tid + it * 256;       // 1024 chunks: 64 rows x 16 float4
        const int row = c >> 4, seg = c & 15;
        const int tok = x[z * SRCN + x0 + row];
        const float4 v = *(const float4*)(F + (size_t)tok * DMOD + d0 + seg * 4);
        ushort4 o;
        o.x = f2b(v.x); o.y = f2b(v.y); o.z = f2b(v.z); o.w = f2b(v.w);
        *(ushort4*)&t[row][seg * 4] = o;
        *(ushort4*)(xe + (size_t)(z * SRCN + x0 + row) * DMOD + d0 + seg * 4) = o;
    }
    __syncthreads();
    #pragma unroll
    for (int it = 0; it < 2; ++it) {
        const int c = tid + it * 256;       // 512 outs: 64 d x 8 seg
        const int d = c >> 3, seg = c & 7;
        ushort4 o0, o1;
        o0.x = t[seg * 8 + 0][d]; o0.y = t[seg * 8 + 1][d];
        o0.z = t[seg * 8 + 2][d]; o0.w = t[seg * 8 + 3][d];
        o1.x = t[seg * 8 + 4][d]; o1.y = t[seg * 8 + 5][d];
        o1.z = t[seg * 8 + 6][d]; o1.w = t[seg * 8 + 7][d];
        ushort* dst = xet + (size_t)(z * DMOD + d0 + d) * SRCN + x0 + seg * 8;
        *(ushort4*)dst = o0; *(ushort4*)(dst + 4) = o1;
    }
}

// ---------------------------------------------------------------------------
// GEMM2: a[b][128][1024] = py_b @ xe_b^T (K=512), mask fused, fp32 out.
// Tile 64m x 32n, grid 2048 (8 blocks/CU), per-batch XCD swizzle.
// ---------------------------------------------------------------------------
__global__ __launch_bounds__(256) void k_gemm_sc(
    const ushort* __restrict__ py, const int* __restrict__ x,
    const ushort* __restrict__ xe, float* __restrict__ a_out)
{
    __shared__ ushort As[8 * 512];   // 64 rows: [kc][m][8]
    __shared__ ushort Bs[8 * 256];   // 32 rows: [kc][n][8]
    const int f = blockIdx.x;        // 0..2047
    const int h = f >> 3;
    const int n = h & 31;
    const int m = (h >> 5) & 1;
    const int b = (f & 7) + 8 * (h >> 6);
    const int tid = threadIdx.x;
    const int w = tid >> 6, lane = tid & 63;
    const int l15 = lane & 15, q = lane >> 4;
    const int wm = w >> 1, wn = w & 1;
    const int m0 = m * 64, n0 = n * 32;

    const ushort* Arow = py + (size_t)(b * SEQL + m0 + lane) * DMOD;
    // B chunk cc: lane<32 -> (nrow=lane, kc=2cc); lane>=32 -> (nrow=lane-32, kc=2cc+1)
    const ushort* Bptr = xe + (size_t)(b * SRCN + n0 + (lane & 31)) * DMOD + (lane >> 5) * 8;

    floatx4 acc[2];
    acc[0] = (floatx4){0.f, 0.f, 0.f, 0.f};
    acc[1] = (floatx4){0.f, 0.f, 0.f, 0.f};

    for (int kk = 0; kk < DMOD; kk += 64) {
        __syncthreads();
        #pragma unroll
        for (int i = 0; i < 2; ++i) {
            const int cc = w * 2 + i;
            gload_lds16(Arow + kk + cc * 8, (void*)(As + cc * 512));
        }
        gload_lds16(Bptr + kk + w * 16, (void*)(Bs + w * 512));
        __syncthreads();
        #pragma unroll
        for (int s2 = 0; s2 < 2; ++s2) {
            const int kc = s2 * 4 + q;
            short8 af[2], bf;
            af[0] = *(const short8*)(As + kc * 512 + (wm * 32 + l15) * 8);
            af[1] = *(const short8*)(As + kc * 512 + (wm * 32 + 16 + l15) * 8);
            bf    = *(const short8*)(Bs + kc * 256 + (wn * 16 + l15) * 8);
            acc[0] = __builtin_amdgcn_mfma_f32_16x16x32_bf16(af[0], bf, acc[0], 0, 0, 0);
            acc[1] = __builtin_amdgcn_mfma_f32_16x16x32_bf16(af[1], bf, acc[1], 0, 0, 0);
        }
    }

    const int col = n0 + wn * 16 + l15;
    const float msk = (x[b * SRCN + col] == 0) ? -1e9f : 0.0f;
    #pragma unroll
    for (int mi = 0; mi < 2; ++mi) {
        const int row0 = m0 + wm * 32 + mi * 16 + q * 4;
        #pragma unroll
        for (int r = 0; r < 4; ++r)
            a_out[((size_t)b * SEQL + row0 + r) * SRCN + col] = acc[mi][r] + msk;
    }
}

// ---------------------------------------------------------------------------
// Row softmax over 1024 (mask already applied); fp32 in place + bf16 copy
// ---------------------------------------------------------------------------
__global__ __launch_bounds__(256) void k_softmax(
    float* __restrict__ a, ushort* __restrict__ abf)
{
    const int row = blockIdx.x;          // b*128+s
    float* p = a + (size_t)row * SRCN;
    ushort* pb = abf + (size_t)row * SRCN;
    const int tid = threadIdx.x;
    const int wave = tid >> 6, lane = tid & 63;

    float4 v = *(const float4*)(p + tid * 4);

    float mx = fmaxf(fmaxf(v.x, v.y), fmaxf(v.z, v.w));
    #pragma unroll
    for (int off = 32; off > 0; off >>= 1)
        mx = fmaxf(mx, __shfl_down(mx, off, 64));
    __shared__ float redm[4];
    if (lane == 0) redm[wave] = mx;
    __syncthreads();
    mx = fmaxf(fmaxf(redm[0], redm[1]), fmaxf(redm[2], redm[3]));

    const float e0 = __expf(v.x - mx);
    const float e1 = __expf(v.y - mx);
    const float e2 = __expf(v.z - mx);
    const float e3 = __expf(v.w - mx);

    float sm = e0 + e1 + e2 + e3;
    #pragma unroll
    for (int off = 32; off > 0; off >>= 1)
        sm += __shfl_down(sm, off, 64);
    __shared__ float reds[4];
    if (lane == 0) reds[wave] = sm;
    __syncthreads();
    sm = reds[0] + reds[1] + reds[2] + reds[3];

    const float inv = 1.0f / sm;
    float4 o;
    o.x = e0 * inv; o.y = e1 * inv; o.z = e2 * inv; o.w = e3 * inv;
    *(float4*)(p + tid * 4) = o;
    ushort4 ob;
    ob.x = f2b(o.x); ob.y = f2b(o.y); ob.z = f2b(o.z); ob.w = f2b(o.w);
    *(ushort4*)(pb + tid * 4) = ob;
}

// ---------------------------------------------------------------------------
// GEMM3: out[b][128][512] = abf_b @ xet_b^T (K=1024), fp32 out.
// Tile 32m x 64n, grid 1024 (4 blocks/CU), per-batch XCD swizzle.
// ---------------------------------------------------------------------------
__global__ __launch_bounds__(256) void k_gemm_out(
    const ushort* __restrict__ abf, const ushort* __restrict__ xet,
    float* __restrict__ outp)
{
    __shared__ ushort As[8 * 256];   // 32 rows: [kc][m][8]
    __shared__ ushort Bs[8 * 512];   // 64 rows: [kc][n][8]
    const int f = blockIdx.x;        // 0..1023
    const int h = f >> 3;
    const int n = h & 7;
    const int m = (h >> 3) & 3;
    const int b = (f & 7) + 8 * (h >> 5);
    const int tid = threadIdx.x;
    const int w = tid >> 6, lane = tid & 63;
    const int l15 = lane & 15, q = lane >> 4;
    const int wm = w >> 1, wn = w & 1;
    const int m0 = m * 32, n0 = n * 64;

    const ushort* Aptr = abf + (size_t)(b * SEQL + m0 + (lane & 31)) * SRCN + (lane >> 5) * 8;
    const ushort* Brow = xet + (size_t)(b * DMOD + n0 + lane) * SRCN;

    floatx4 acc[2];
    acc[0] = (floatx4){0.f, 0.f, 0.f, 0.f};
    acc[1] = (floatx4){0.f, 0.f, 0.f, 0.f};

    for (int kk = 0; kk < SRCN; kk += 64) {
        __syncthreads();
        gload_lds16(Aptr + kk + w * 16, (void*)(As + w * 512));
        #pragma unroll
        for (int i = 0; i < 2; ++i) {
            const int cc = w * 2 + i;
            gload_lds16(Brow + kk + cc * 8, (void*)(Bs + cc * 512));
        }
        __syncthreads();
        #pragma unroll
        for (int s2 = 0; s2 < 2; ++s2) {
            const int kc = s2 * 4 + q;
            short8 af, bf[2];
            af    = *(const short8*)(As + kc * 256 + (wm * 16 + l15) * 8);
            bf[0] = *(const short8*)(Bs + kc * 512 + (wn * 32 + l15) * 8);
            bf[1] = *(const short8*)(Bs + kc * 512 + (wn * 32 + 16 + l15) * 8);
            acc[0] = __builtin_amdgcn_mfma_f32_16x16x32_bf16(af, bf[0], acc[0], 0, 0, 0);
            acc[1] = __builtin_amdgcn_mfma_f32_16x16x32_bf16(af, bf[1], acc[1], 0, 0, 0);
        }
    }

    const int row0 = m0 + wm * 16 + q * 4;
    #pragma unroll
    for (int ni = 0; ni < 2; ++ni) {
        const int col = n0 + wn * 32 + ni * 16 + l15;
        #pragma unroll
        for (int r = 0; r < 4; ++r)
            outp[((size_t)b * SEQL + row0 + r) * DMOD + col] = acc[ni][r];
    }
}

// ---------------------------------------------------------------------------
extern "C" void kernel_launch(void* const* d_in, const int* in_sizes, int n_in,
                              void* d_out, int out_size, void* d_ws, size_t ws_size,
                              hipStream_t stream)
{
    const int*   x    = (const int*)d_in[0];    // [32,1024]
    const int*   yc   = (const int*)d_in[1];    // [32,640]
    const float* Femb = (const float*)d_in[2];  // [32000,512]
    const float* Gemb = (const float*)d_in[3];  // [32000,512]
    const float* Pw   = (const float*)d_in[4];  // [2560,512]
    const float* Pb   = (const float*)d_in[5];  // [512]

    float* out_p = (float*)d_out;                         // [32,128,512]
    float* a_p   = out_p + (size_t)BATCH * SEQL * DMOD;   // [32,128,1024]

    // Workspace (79.7 MB) with lifetime aliasing:
    //   yce  [0,        20971520)  live: k_yce .. gemm_py
    //   pwt  [20971520, 23592960)  live: k_pwt .. gemm_py
    //   part [23592960, 57147392)  live: gemm_py .. red4   (4 x 8.39 MB fp32)
    //   xe   [0,        33554432)  live: xe2 .. gemm_sc    (aliases yce/pwt/part-head)
    //   xet  [33554432, 67108864)  live: xe2 .. gemm_out   (aliases part-tail)
    //   py   [67108864, 71303168)  live: red4 .. gemm_sc
    //   abf  [71303168, 79691776)  live: softmax .. gemm_out
    char* ws = (char*)d_ws;
    ushort* yce  = (ushort*)(ws);
    ushort* pwt  = (ushort*)(ws + 20971520);
    float*  part = (float*) (ws + 23592960);
    ushort* xe   = (ushort*)(ws);
    ushort* xet  = (ushort*)(ws + 33554432);
    ushort* py   = (ushort*)(ws + 67108864);
    ushort* abf  = (ushort*)(ws + 71303168);

    dim3 blk(256);
    k_yce<<<dim3(4096), blk, 0, stream>>>(yc, Gemb, yce);
    k_pwt<<<dim3(40, 8), blk, 0, stream>>>(Pw, pwt);

    // GEMM1 split-K=4: 2048 blocks (8/CU), XCD-swizzled
    k_gemm_py<<<dim3(2048), blk, 0, stream>>>(yce, pwt, part);
    k_red4<<<dim3(2048), blk, 0, stream>>>(part, Pb, py);

    // gather F -> xe + xet (after red4: may overwrite yce/pwt/part)
    k_xe2<<<dim3(16, 8, 32), blk, 0, stream>>>(x, Femb, xe, xet);

    // GEMM2: 2048 blocks (8/CU), mask fused
    k_gemm_sc<<<dim3(2048), blk, 0, stream>>>(py, x, xe, a_p);
    k_softmax<<<dim3(4096), blk, 0, stream>>>(a_p, abf);
    // GEMM3: 1024 blocks (4/CU)
    k_gemm_out<<<dim3(1024), blk, 0, stream>>>(abf, xet, out_p);
}

// Round 5
// 223.735 us; speedup vs baseline: 1.2833x; 1.2417x over previous
//
#include <hip/hip_runtime.h>
#include <hip/hip_bf16.h>
#include <stdint.h>

#define BATCH 32
#define SRCN 1024
#define SEQL 128
#define CTXN 5
#define DMOD 512

typedef __attribute__((ext_vector_type(8))) short short8;
typedef __attribute__((ext_vector_type(4))) float floatx4;

typedef __attribute__((address_space(3))) void lds_t;
typedef __attribute__((address_space(1))) void glb_t;

__device__ __forceinline__ void gload_lds16(const void* g, void* l) {
    __builtin_amdgcn_global_load_lds((const glb_t*)g, (lds_t*)l, 16, 0, 0);
}

__device__ __forceinline__ ushort f2b(float f) {
    __hip_bfloat16 h = __float2bfloat16(f);
    return *reinterpret_cast<ushort*>(&h);
}

// Swizzled LDS slot for (tile-local row m, k-seg sg) : slot = m*8 + (sg^(m&7)),
// each slot 8 ushorts (16B). Staging chunk cc (1KB): lane i stages
// row cc*8+(i>>3), seg (i&7)^(i>>3)  -> 8 contiguous 128B runs (coalesced).
#define LSLOT(m, sg) ((((m) << 3) | ((sg) ^ ((m) & 7))) << 3)

// ---------------------------------------------------------------------------
// Gather+convert yce[4096][2560] bf16 (5 G_emb rows per (b,s))
// ---------------------------------------------------------------------------
__global__ __launch_bounds__(256) void k_yce(
    const int* __restrict__ yc, const float* __restrict__ G,
    ushort* __restrict__ yce)
{
    const int r = blockIdx.x;            // 0..4095 = b*128+s
    const int b = r >> 7, s = r & 127;
    const int tid = threadIdx.x;
    for (int i = tid; i < 640; i += 256) {
        const int c = i >> 7;            // context slot 0..4
        const int tok = yc[b * (SEQL * CTXN) + s * CTXN + c];
        const float4 v = *(const float4*)(G + (size_t)tok * DMOD + (i & 127) * 4);
        ushort4 o;
        o.x = f2b(v.x); o.y = f2b(v.y); o.z = f2b(v.z); o.w = f2b(v.w);
        *(ushort4*)(yce + (size_t)r * 2560 + i * 4) = o;
    }
}

// ---------------------------------------------------------------------------
// Transpose+convert P_w [2560][512] f32 -> pwt [512][2560] bf16
// ---------------------------------------------------------------------------
__global__ __launch_bounds__(256) void k_pwt(
    const float* __restrict__ Pw, ushort* __restrict__ Pwt)
{
    __shared__ float t[64][68];
    const int k0 = blockIdx.x * 64, n0 = blockIdx.y * 64;
    const int tid = threadIdx.x;
    #pragma unroll
    for (int it = 0; it < 4; ++it) {
        const int c = tid + it * 256;
        const int kr = c >> 4, c4 = c & 15;
        const float4 v = *(const float4*)(Pw + (size_t)(k0 + kr) * DMOD + n0 + c4 * 4);
        t[kr][c4 * 4 + 0] = v.x; t[kr][c4 * 4 + 1] = v.y;
        t[kr][c4 * 4 + 2] = v.z; t[kr][c4 * 4 + 3] = v.w;
    }
    __syncthreads();
    #pragma unroll
    for (int it = 0; it < 2; ++it) {
        const int c = tid + it * 256;
        const int n = c >> 3, seg = c & 7;
        ushort4 o0, o1;
        o0.x = f2b(t[seg * 8 + 0][n]); o0.y = f2b(t[seg * 8 + 1][n]);
        o0.z = f2b(t[seg * 8 + 2][n]); o0.w = f2b(t[seg * 8 + 3][n]);
        o1.x = f2b(t[seg * 8 + 4][n]); o1.y = f2b(t[seg * 8 + 5][n]);
        o1.z = f2b(t[seg * 8 + 6][n]); o1.w = f2b(t[seg * 8 + 7][n]);
        ushort* dst = Pwt + (size_t)(n0 + n) * 2560 + k0 + seg * 8;
        *(ushort4*)dst = o0; *(ushort4*)(dst + 4) = o1;
    }
}

// ---------------------------------------------------------------------------
// GEMM1 (split-K=2, XCD-swizzled): part[ks] = yce[., ks*1280:] @ pwt^T slice
// 64x64 tile, BK=64, coalesced+swizzled staging.
// ---------------------------------------------------------------------------
__global__ __launch_bounds__(256) void k_gemm_py(
    const ushort* __restrict__ yce, const ushort* __restrict__ pwt,
    float* __restrict__ part)
{
    __shared__ ushort As[8 * 512];
    __shared__ ushort Bs[8 * 512];
    const int f = blockIdx.x;        // 0..1023
    const int n  = (f >> 3) & 7;
    const int m  = (f & 7) | (((f >> 6) & 7) << 3);
    const int ks = f >> 9;
    const int tid = threadIdx.x;
    const int w = tid >> 6, lane = tid & 63;
    const int l15 = lane & 15, q = lane >> 4;
    const int wm = w >> 1, wn = w & 1;
    const int m0 = m * 64, n0 = n * 64, koff = ks * 1280;

    // per-lane staging offsets: row-in-chunk + swizzled k-seg
    const int sr = lane >> 3;                       // 0..7
    const int ssg = ((lane & 7) ^ sr) * 8;          // element offset

    const ushort* Abase = yce + (size_t)(m0 + sr) * 2560 + koff + ssg;
    const ushort* Bbase = pwt + (size_t)(n0 + sr) * 2560 + koff + ssg;

    floatx4 acc[2][2];
    #pragma unroll
    for (int mi = 0; mi < 2; ++mi)
        #pragma unroll
        for (int ni = 0; ni < 2; ++ni)
            acc[mi][ni] = (floatx4){0.f, 0.f, 0.f, 0.f};

    for (int kk = 0; kk < 1280; kk += 64) {
        __syncthreads();
        #pragma unroll
        for (int i = 0; i < 2; ++i) {
            const int cc = w * 2 + i;
            gload_lds16(Abase + (size_t)(cc * 8) * 2560 + kk, (void*)(As + cc * 512));
            gload_lds16(Bbase + (size_t)(cc * 8) * 2560 + kk, (void*)(Bs + cc * 512));
        }
        __syncthreads();
        #pragma unroll
        for (int s2 = 0; s2 < 2; ++s2) {
            const int sg = s2 * 4 + q;
            short8 af[2], bf[2];
            #pragma unroll
            for (int mi = 0; mi < 2; ++mi)
                af[mi] = *(const short8*)(As + LSLOT(wm * 32 + mi * 16 + l15, sg));
            #pragma unroll
            for (int ni = 0; ni < 2; ++ni)
                bf[ni] = *(const short8*)(Bs + LSLOT(wn * 32 + ni * 16 + l15, sg));
            #pragma unroll
            for (int mi = 0; mi < 2; ++mi)
                #pragma unroll
                for (int ni = 0; ni < 2; ++ni)
                    acc[mi][ni] = __builtin_amdgcn_mfma_f32_16x16x32_bf16(
                        af[mi], bf[ni], acc[mi][ni], 0, 0, 0);
        }
    }

    float* dst = part + (size_t)ks * (4096LL * DMOD);
    #pragma unroll
    for (int ni = 0; ni < 2; ++ni) {
        const int col = n0 + wn * 32 + ni * 16 + l15;
        #pragma unroll
        for (int mi = 0; mi < 2; ++mi) {
            const int row0 = m0 + wm * 32 + mi * 16 + q * 4;
            #pragma unroll
            for (int r = 0; r < 4; ++r)
                dst[(size_t)(row0 + r) * DMOD + col] = acc[mi][ni][r];
        }
    }
}

// ---------------------------------------------------------------------------
// Reduce 2 split-K partials + bias -> py bf16 [4096][512]
// ---------------------------------------------------------------------------
__global__ __launch_bounds__(256) void k_red2(
    const float* __restrict__ part, const float* __restrict__ Pb,
    ushort* __restrict__ py)
{
    const long long SL = 4096LL * DMOD;
    const int i = blockIdx.x * 256 + threadIdx.x;   // vec4 id, 524288 total
    const float4 a = *(const float4*)(part + (size_t)i * 4);
    const float4 b = *(const float4*)(part + SL + (size_t)i * 4);
    const float4 bias = *(const float4*)(Pb + ((i * 4) & 511));
    ushort4 o;
    o.x = f2b(a.x + b.x + bias.x);
    o.y = f2b(a.y + b.y + bias.y);
    o.z = f2b(a.z + b.z + bias.z);
    o.w = f2b(a.w + b.w + bias.w);
    *(ushort4*)(py + (size_t)i * 4) = o;
}

// ---------------------------------------------------------------------------
// Gather F fp32 rows once -> xe[b][x][d] bf16 AND xet[b][d][x] bf16.
// ---------------------------------------------------------------------------
__global__ __launch_bounds__(256) void k_xe2(
    const int* __restrict__ x, const float* __restrict__ F,
    ushort* __restrict__ xe, ushort* __restrict__ xet)
{
    __shared__ ushort t[64][72];
    const int z = blockIdx.z;
    const int x0 = blockIdx.x * 64, d0 = blockIdx.y * 64;
    const int tid = threadIdx.x;
    #pragma unroll
    for (int it = 0; it < 4; ++it) {
        const int c = tid + it * 256;       // 1024 chunks: 64 rows x 16 float4
        const int row = c >> 4, seg = c & 15;
        const int tok = x[z * SRCN + x0 + row];
        const float4 v = *(const float4*)(F + (size_t)tok * DMOD + d0 + seg * 4);
        ushort4 o;
        o.x = f2b(v.x); o.y = f2b(v.y); o.z = f2b(v.z); o.w = f2b(v.w);
        *(ushort4*)&t[row][seg * 4] = o;
        *(ushort4*)(xe + (size_t)(z * SRCN + x0 + row) * DMOD + d0 + seg * 4) = o;
    }
    __syncthreads();
    #pragma unroll
    for (int it = 0; it < 2; ++it) {
        const int c = tid + it * 256;       // 512 outs: 64 d x 8 seg
        const int d = c >> 3, seg = c & 7;
        ushort4 o0, o1;
        o0.x = t[seg * 8 + 0][d]; o0.y = t[seg * 8 + 1][d];
        o0.z = t[seg * 8 + 2][d]; o0.w = t[seg * 8 + 3][d];
        o1.x = t[seg * 8 + 4][d]; o1.y = t[seg * 8 + 5][d];
        o1.z = t[seg * 8 + 6][d]; o1.w = t[seg * 8 + 7][d];
        ushort* dst = xet + (size_t)(z * DMOD + d0 + d) * SRCN + x0 + seg * 8;
        *(ushort4*)dst = o0; *(ushort4*)(dst + 4) = o1;
    }
}

// ---------------------------------------------------------------------------
// GEMM2: a[b][128][1024] = py_b @ xe_b^T (K=512), mask fused, fp32 out.
// Tile 64m x 32n, 2048 blocks, coalesced+swizzled staging.
// ---------------------------------------------------------------------------
__global__ __launch_bounds__(256) void k_gemm_sc(
    const ushort* __restrict__ py, const int* __restrict__ x,
    const ushort* __restrict__ xe, float* __restrict__ a_out)
{
    __shared__ ushort As[8 * 512];   // 64 rows
    __shared__ ushort Bs[4 * 512];   // 32 rows
    const int f = blockIdx.x;        // 0..2047
    const int h = f >> 3;
    const int n = h & 31;
    const int m = (h >> 5) & 1;
    const int b = (f & 7) + 8 * (h >> 6);
    const int tid = threadIdx.x;
    const int w = tid >> 6, lane = tid & 63;
    const int l15 = lane & 15, q = lane >> 4;
    const int wm = w >> 1, wn = w & 1;
    const int m0 = m * 64, n0 = n * 32;

    const int sr = lane >> 3;
    const int ssg = ((lane & 7) ^ sr) * 8;

    const ushort* Abase = py + (size_t)(b * SEQL + m0 + sr) * DMOD + ssg;
    const ushort* Bbase = xe + (size_t)(b * SRCN + n0 + sr) * DMOD + ssg;

    floatx4 acc[2];
    acc[0] = (floatx4){0.f, 0.f, 0.f, 0.f};
    acc[1] = (floatx4){0.f, 0.f, 0.f, 0.f};

    for (int kk = 0; kk < DMOD; kk += 64) {
        __syncthreads();
        #pragma unroll
        for (int i = 0; i < 2; ++i) {
            const int cc = w * 2 + i;
            gload_lds16(Abase + (size_t)(cc * 8) * DMOD + kk, (void*)(As + cc * 512));
        }
        gload_lds16(Bbase + (size_t)(w * 8) * DMOD + kk, (void*)(Bs + w * 512));
        __syncthreads();
        #pragma unroll
        for (int s2 = 0; s2 < 2; ++s2) {
            const int sg = s2 * 4 + q;
            short8 af[2], bf;
            af[0] = *(const short8*)(As + LSLOT(wm * 32 + l15, sg));
            af[1] = *(const short8*)(As + LSLOT(wm * 32 + 16 + l15, sg));
            bf    = *(const short8*)(Bs + LSLOT(wn * 16 + l15, sg));
            acc[0] = __builtin_amdgcn_mfma_f32_16x16x32_bf16(af[0], bf, acc[0], 0, 0, 0);
            acc[1] = __builtin_amdgcn_mfma_f32_16x16x32_bf16(af[1], bf, acc[1], 0, 0, 0);
        }
    }

    const int col = n0 + wn * 16 + l15;
    const float msk = (x[b * SRCN + col] == 0) ? -1e9f : 0.0f;
    #pragma unroll
    for (int mi = 0; mi < 2; ++mi) {
        const int row0 = m0 + wm * 32 + mi * 16 + q * 4;
        #pragma unroll
        for (int r = 0; r < 4; ++r)
            a_out[((size_t)b * SEQL + row0 + r) * SRCN + col] = acc[mi][r] + msk;
    }
}

// ---------------------------------------------------------------------------
// Row softmax over 1024 (mask already applied); fp32 in place + bf16 copy
// ---------------------------------------------------------------------------
__global__ __launch_bounds__(256) void k_softmax(
    float* __restrict__ a, ushort* __restrict__ abf)
{
    const int row = blockIdx.x;          // b*128+s
    float* p = a + (size_t)row * SRCN;
    ushort* pb = abf + (size_t)row * SRCN;
    const int tid = threadIdx.x;
    const int wave = tid >> 6, lane = tid & 63;

    float4 v = *(const float4*)(p + tid * 4);

    float mx = fmaxf(fmaxf(v.x, v.y), fmaxf(v.z, v.w));
    #pragma unroll
    for (int off = 32; off > 0; off >>= 1)
        mx = fmaxf(mx, __shfl_down(mx, off, 64));
    __shared__ float redm[4];
    if (lane == 0) redm[wave] = mx;
    __syncthreads();
    mx = fmaxf(fmaxf(redm[0], redm[1]), fmaxf(redm[2], redm[3]));

    const float e0 = __expf(v.x - mx);
    const float e1 = __expf(v.y - mx);
    const float e2 = __expf(v.z - mx);
    const float e3 = __expf(v.w - mx);

    float sm = e0 + e1 + e2 + e3;
    #pragma unroll
    for (int off = 32; off > 0; off >>= 1)
        sm += __shfl_down(sm, off, 64);
    __shared__ float reds[4];
    if (lane == 0) reds[wave] = sm;
    __syncthreads();
    sm = reds[0] + reds[1] + reds[2] + reds[3];

    const float inv = 1.0f / sm;
    float4 o;
    o.x = e0 * inv; o.y = e1 * inv; o.z = e2 * inv; o.w = e3 * inv;
    *(float4*)(p + tid * 4) = o;
    ushort4 ob;
    ob.x = f2b(o.x); ob.y = f2b(o.y); ob.z = f2b(o.z); ob.w = f2b(o.w);
    *(ushort4*)(pb + tid * 4) = ob;
}

// ---------------------------------------------------------------------------
// GEMM3: out[b][128][512] = abf_b @ xet_b^T (K=1024), fp32 out.
// Tile 32m x 64n, 1024 blocks, coalesced+swizzled staging.
// ---------------------------------------------------------------------------
__global__ __launch_bounds__(256) void k_gemm_out(
    const ushort* __restrict__ abf, const ushort* __restrict__ xet,
    float* __restrict__ outp)
{
    __shared__ ushort As[4 * 512];   // 32 rows
    __shared__ ushort Bs[8 * 512];   // 64 rows
    const int f = blockIdx.x;        // 0..1023
    const int h = f >> 3;
    const int n = h & 7;
    const int m = (h >> 3) & 3;
    const int b = (f & 7) + 8 * (h >> 5);
    const int tid = threadIdx.x;
    const int w = tid >> 6, lane = tid & 63;
    const int l15 = lane & 15, q = lane >> 4;
    const int wm = w >> 1, wn = w & 1;
    const int m0 = m * 32, n0 = n * 64;

    const int sr = lane >> 3;
    const int ssg = ((lane & 7) ^ sr) * 8;

    const ushort* Abase = abf + (size_t)(b * SEQL + m0 + sr) * SRCN + ssg;
    const ushort* Bbase = xet + (size_t)(b * DMOD + n0 + sr) * SRCN + ssg;

    floatx4 acc[2];
    acc[0] = (floatx4){0.f, 0.f, 0.f, 0.f};
    acc[1] = (floatx4){0.f, 0.f, 0.f, 0.f};

    for (int kk = 0; kk < SRCN; kk += 64) {
        __syncthreads();
        gload_lds16(Abase + (size_t)(w * 8) * SRCN + kk, (void*)(As + w * 512));
        #pragma unroll
        for (int i = 0; i < 2; ++i) {
            const int cc = w * 2 + i;
            gload_lds16(Bbase + (size_t)(cc * 8) * SRCN + kk, (void*)(Bs + cc * 512));
        }
        __syncthreads();
        #pragma unroll
        for (int s2 = 0; s2 < 2; ++s2) {
            const int sg = s2 * 4 + q;
            short8 af, bf[2];
            af    = *(const short8*)(As + LSLOT(wm * 16 + l15, sg));
            bf[0] = *(const short8*)(Bs + LSLOT(wn * 32 + l15, sg));
            bf[1] = *(const short8*)(Bs + LSLOT(wn * 32 + 16 + l15, sg));
            acc[0] = __builtin_amdgcn_mfma_f32_16x16x32_bf16(af, bf[0], acc[0], 0, 0, 0);
            acc[1] = __builtin_amdgcn_mfma_f32_16x16x32_bf16(af, bf[1], acc[1], 0, 0, 0);
        }
    }

    const int row0 = m0 + wm * 16 + q * 4;
    #pragma unroll
    for (int ni = 0; ni < 2; ++ni) {
        const int col = n0 + wn * 32 + ni * 16 + l15;
        #pragma unroll
        for (int r = 0; r < 4; ++r)
            outp[((size_t)b * SEQL + row0 + r) * DMOD + col] = acc[ni][r];
    }
}

// ---------------------------------------------------------------------------
extern "C" void kernel_launch(void* const* d_in, const int* in_sizes, int n_in,
                              void* d_out, int out_size, void* d_ws, size_t ws_size,
                              hipStream_t stream)
{
    const int*   x    = (const int*)d_in[0];    // [32,1024]
    const int*   yc   = (const int*)d_in[1];    // [32,640]
    const float* Femb = (const float*)d_in[2];  // [32000,512]
    const float* Gemb = (const float*)d_in[3];  // [32000,512]
    const float* Pw   = (const float*)d_in[4];  // [2560,512]
    const float* Pb   = (const float*)d_in[5];  // [512]

    float* out_p = (float*)d_out;                         // [32,128,512]
    float* a_p   = out_p + (size_t)BATCH * SEQL * DMOD;   // [32,128,1024]

    // Workspace with lifetime aliasing:
    //   yce  [0,        20971520)  live: k_yce .. gemm_py
    //   pwt  [20971520, 23592960)  live: k_pwt .. gemm_py
    //   part [23592960, 40370176)  live: gemm_py .. red2   (2 x 8.39 MB fp32)
    //   xe   [0,        33554432)  live: xe2 .. gemm_sc
    //   xet  [33554432, 67108864)  live: xe2 .. gemm_out
    //   py   [67108864, 71303168)  live: red2 .. gemm_sc
    //   abf  [71303168, 79691776)  live: softmax .. gemm_out
    char* ws = (char*)d_ws;
    ushort* yce  = (ushort*)(ws);
    ushort* pwt  = (ushort*)(ws + 20971520);
    float*  part = (float*) (ws + 23592960);
    ushort* xe   = (ushort*)(ws);
    ushort* xet  = (ushort*)(ws + 33554432);
    ushort* py   = (ushort*)(ws + 67108864);
    ushort* abf  = (ushort*)(ws + 71303168);

    dim3 blk(256);
    k_yce<<<dim3(4096), blk, 0, stream>>>(yc, Gemb, yce);
    k_pwt<<<dim3(40, 8), blk, 0, stream>>>(Pw, pwt);

    // GEMM1 split-K=2: 1024 blocks (4/CU), XCD-swizzled
    k_gemm_py<<<dim3(1024), blk, 0, stream>>>(yce, pwt, part);
    k_red2<<<dim3(2048), blk, 0, stream>>>(part, Pb, py);

    // gather F -> xe + xet (after red2: may overwrite yce/pwt/part)
    k_xe2<<<dim3(16, 8, 32), blk, 0, stream>>>(x, Femb, xe, xet);

    // GEMM2: 2048 blocks (8/CU), mask fused
    k_gemm_sc<<<dim3(2048), blk, 0, stream>>>(py, x, xe, a_p);
    k_softmax<<<dim3(4096), blk, 0, stream>>>(a_p, abf);
    // GEMM3: 1024 blocks (4/CU)
    k_gemm_out<<<dim3(1024), blk, 0, stream>>>(abf, xet, out_p);
}

// Round 6
// 220.535 us; speedup vs baseline: 1.3020x; 1.0145x over previous
//
#include <hip/hip_runtime.h>
#include <hip/hip_bf16.h>
#include <stdint.h>

#define BATCH 32
#define SRCN 1024
#define SEQL 128
#define CTXN 5
#define DMOD 512

typedef __attribute__((ext_vector_type(8))) short short8;
typedef __attribute__((ext_vector_type(4))) float floatx4;

typedef __attribute__((address_space(3))) void lds_t;
typedef __attribute__((address_space(1))) void glb_t;

__device__ __forceinline__ void gload_lds16(const void* g, void* l) {
    __builtin_amdgcn_global_load_lds((const glb_t*)g, (lds_t*)l, 16, 0, 0);
}

__device__ __forceinline__ ushort f2b(float f) {
    __hip_bfloat16 h = __float2bfloat16(f);
    return *reinterpret_cast<ushort*>(&h);
}

// Swizzled LDS slot for (tile-local row m, k-seg sg): slot = m*8 + (sg^(m&7)),
// slot = 8 ushorts (16B). Staging chunk cc (1KB = 8 rows x 64k): lane i stages
// row cc*8+(i>>3), k-seg (i&7)^(i>>3) -> 8 contiguous 128B runs, and the LDS
// dest is exactly chunkbase + lane*16 (wave-uniform base + lane*size).
#define LSLOT(m, sg) ((((m) << 3) | ((sg) ^ ((m) & 7))) << 3)

// ---------------------------------------------------------------------------
// Prep (merged): blocks [0,4096) gather yce; blocks [4096,4416) transpose P_w.
// ---------------------------------------------------------------------------
__global__ __launch_bounds__(256) void k_prep(
    const int* __restrict__ yc, const float* __restrict__ G,
    ushort* __restrict__ yce,
    const float* __restrict__ Pw, ushort* __restrict__ Pwt)
{
    const int tid = threadIdx.x;
    if (blockIdx.x < 4096) {
        const int r = blockIdx.x;            // b*128+s
        const int b = r >> 7, s = r & 127;
        for (int i = tid; i < 640; i += 256) {
            const int c = i >> 7;            // context slot 0..4
            const int tok = yc[b * (SEQL * CTXN) + s * CTXN + c];
            const float4 v = *(const float4*)(G + (size_t)tok * DMOD + (i & 127) * 4);
            ushort4 o;
            o.x = f2b(v.x); o.y = f2b(v.y); o.z = f2b(v.z); o.w = f2b(v.w);
            *(ushort4*)(yce + (size_t)r * 2560 + i * 4) = o;
        }
    } else {
        __shared__ float t[64][68];
        const int bid = blockIdx.x - 4096;   // 0..319
        const int k0 = (bid % 40) * 64, n0 = (bid / 40) * 64;
        #pragma unroll
        for (int it = 0; it < 4; ++it) {
            const int c = tid + it * 256;
            const int kr = c >> 4, c4 = c & 15;
            const float4 v = *(const float4*)(Pw + (size_t)(k0 + kr) * DMOD + n0 + c4 * 4);
            t[kr][c4 * 4 + 0] = v.x; t[kr][c4 * 4 + 1] = v.y;
            t[kr][c4 * 4 + 2] = v.z; t[kr][c4 * 4 + 3] = v.w;
        }
        __syncthreads();
        #pragma unroll
        for (int it = 0; it < 2; ++it) {
            const int c = tid + it * 256;
            const int n = c >> 3, seg = c & 7;
            ushort4 o0, o1;
            o0.x = f2b(t[seg * 8 + 0][n]); o0.y = f2b(t[seg * 8 + 1][n]);
            o0.z = f2b(t[seg * 8 + 2][n]); o0.w = f2b(t[seg * 8 + 3][n]);
            o1.x = f2b(t[seg * 8 + 4][n]); o1.y = f2b(t[seg * 8 + 5][n]);
            o1.z = f2b(t[seg * 8 + 6][n]); o1.w = f2b(t[seg * 8 + 7][n]);
            ushort* dst = Pwt + (size_t)(n0 + n) * 2560 + k0 + seg * 8;
            *(ushort4*)dst = o0; *(ushort4*)(dst + 4) = o1;
        }
    }
}

// ---------------------------------------------------------------------------
// GEMM1 (split-K=4): part[ks] = yce[., ks*640:] @ pwt^T slice.
// Tile 128m x 64n, BK=64. 4 waves 2x2, wave tile 64x32 (ratio 6 reads:8 mfma).
// ---------------------------------------------------------------------------
__global__ __launch_bounds__(256) void k_gemm_py(
    const ushort* __restrict__ yce, const ushort* __restrict__ pwt,
    float* __restrict__ part)
{
    __shared__ ushort As[16 * 512];   // 128 rows x 64 k
    __shared__ ushort Bs[8 * 512];    // 64 rows x 64 k
    const int f = blockIdx.x;         // 0..1023
    const int mlo = f & 7;
    const int n   = (f >> 3) & 7;
    const int mhi = (f >> 6) & 3;
    const int ks  = f >> 8;
    const int m = mlo | (mhi << 3);   // 0..31
    const int tid = threadIdx.x;
    const int w = tid >> 6, lane = tid & 63;
    const int l15 = lane & 15, q = lane >> 4;
    const int wm = w >> 1, wn = w & 1;
    const int m0 = m * 128, n0 = n * 64, koff = ks * 640;

    const int sr = lane >> 3;
    const int ssg = ((lane & 7) ^ sr) * 8;

    const ushort* Abase = yce + (size_t)(m0 + sr) * 2560 + koff + ssg;
    const ushort* Bbase = pwt + (size_t)(n0 + sr) * 2560 + koff + ssg;

    floatx4 acc[4][2];
    #pragma unroll
    for (int mi = 0; mi < 4; ++mi)
        #pragma unroll
        for (int ni = 0; ni < 2; ++ni)
            acc[mi][ni] = (floatx4){0.f, 0.f, 0.f, 0.f};

    for (int kk = 0; kk < 640; kk += 64) {
        __syncthreads();
        #pragma unroll
        for (int i = 0; i < 4; ++i) {
            const int cc = w * 4 + i;
            gload_lds16(Abase + (size_t)(cc * 8) * 2560 + kk, (void*)(As + cc * 512));
        }
        #pragma unroll
        for (int i = 0; i < 2; ++i) {
            const int cc = w * 2 + i;
            gload_lds16(Bbase + (size_t)(cc * 8) * 2560 + kk, (void*)(Bs + cc * 512));
        }
        __syncthreads();
        #pragma unroll
        for (int s2 = 0; s2 < 2; ++s2) {
            const int sg = s2 * 4 + q;
            short8 af[4], bf[2];
            #pragma unroll
            for (int mi = 0; mi < 4; ++mi)
                af[mi] = *(const short8*)(As + LSLOT(wm * 64 + mi * 16 + l15, sg));
            #pragma unroll
            for (int ni = 0; ni < 2; ++ni)
                bf[ni] = *(const short8*)(Bs + LSLOT(wn * 32 + ni * 16 + l15, sg));
            #pragma unroll
            for (int mi = 0; mi < 4; ++mi)
                #pragma unroll
                for (int ni = 0; ni < 2; ++ni)
                    acc[mi][ni] = __builtin_amdgcn_mfma_f32_16x16x32_bf16(
                        af[mi], bf[ni], acc[mi][ni], 0, 0, 0);
        }
    }

    float* dst = part + (size_t)ks * (4096LL * DMOD);
    #pragma unroll
    for (int ni = 0; ni < 2; ++ni) {
        const int col = n0 + wn * 32 + ni * 16 + l15;
        #pragma unroll
        for (int mi = 0; mi < 4; ++mi) {
            const int row0 = m0 + wm * 64 + mi * 16 + q * 4;
            #pragma unroll
            for (int r = 0; r < 4; ++r)
                dst[(size_t)(row0 + r) * DMOD + col] = acc[mi][ni][r];
        }
    }
}

// ---------------------------------------------------------------------------
// Reduce 4 split-K partials + bias -> py bf16 [4096][512]
// ---------------------------------------------------------------------------
__global__ __launch_bounds__(256) void k_red4(
    const float* __restrict__ part, const float* __restrict__ Pb,
    ushort* __restrict__ py)
{
    const long long SL = 4096LL * DMOD;
    const int i = blockIdx.x * 256 + threadIdx.x;   // vec4 id, 524288 total
    const float4 a = *(const float4*)(part + (size_t)i * 4);
    const float4 b = *(const float4*)(part + SL + (size_t)i * 4);
    const float4 c = *(const float4*)(part + 2 * SL + (size_t)i * 4);
    const float4 d = *(const float4*)(part + 3 * SL + (size_t)i * 4);
    const float4 bias = *(const float4*)(Pb + ((i * 4) & 511));
    ushort4 o;
    o.x = f2b(a.x + b.x + c.x + d.x + bias.x);
    o.y = f2b(a.y + b.y + c.y + d.y + bias.y);
    o.z = f2b(a.z + b.z + c.z + d.z + bias.z);
    o.w = f2b(a.w + b.w + c.w + d.w + bias.w);
    *(ushort4*)(py + (size_t)i * 4) = o;
}

// ---------------------------------------------------------------------------
// Gather F fp32 rows once -> xe[b][x][d] bf16 AND xet[b][d][x] bf16.
// ---------------------------------------------------------------------------
__global__ __launch_bounds__(256) void k_xe2(
    const int* __restrict__ x, const float* __restrict__ F,
    ushort* __restrict__ xe, ushort* __restrict__ xet)
{
    __shared__ ushort t[64][72];
    const int z = blockIdx.z;
    const int x0 = blockIdx.x * 64, d0 = blockIdx.y * 64;
    const int tid = threadIdx.x;
    #pragma unroll
    for (int it = 0; it < 4; ++it) {
        const int c = tid + it * 256;       // 1024 chunks: 64 rows x 16 float4
        const int row = c >> 4, seg = c & 15;
        const int tok = x[z * SRCN + x0 + row];
        const float4 v = *(const float4*)(F + (size_t)tok * DMOD + d0 + seg * 4);
        ushort4 o;
        o.x = f2b(v.x); o.y = f2b(v.y); o.z = f2b(v.z); o.w = f2b(v.w);
        *(ushort4*)&t[row][seg * 4] = o;
        *(ushort4*)(xe + (size_t)(z * SRCN + x0 + row) * DMOD + d0 + seg * 4) = o;
    }
    __syncthreads();
    #pragma unroll
    for (int it = 0; it < 2; ++it) {
        const int c = tid + it * 256;       // 512 outs: 64 d x 8 seg
        const int d = c >> 3, seg = c & 7;
        ushort4 o0, o1;
        o0.x = t[seg * 8 + 0][d]; o0.y = t[seg * 8 + 1][d];
        o0.z = t[seg * 8 + 2][d]; o0.w = t[seg * 8 + 3][d];
        o1.x = t[seg * 8 + 4][d]; o1.y = t[seg * 8 + 5][d];
        o1.z = t[seg * 8 + 6][d]; o1.w = t[seg * 8 + 7][d];
        ushort* dst = xet + (size_t)(z * DMOD + d0 + d) * SRCN + x0 + seg * 8;
        *(ushort4*)dst = o0; *(ushort4*)(dst + 4) = o1;
    }
}

// ---------------------------------------------------------------------------
// GEMM2: a[b][0:128][n0:n0+64] = py_b @ xe_b^T (K=512), mask fused, fp32 out.
// Tile 128m x 64n, 512 blocks, per-batch XCD swizzle (f&7 == b&7).
// ---------------------------------------------------------------------------
__global__ __launch_bounds__(256) void k_gemm_sc(
    const ushort* __restrict__ py, const int* __restrict__ x,
    const ushort* __restrict__ xe, float* __restrict__ a_out)
{
    __shared__ ushort As[16 * 512];   // 128 rows x 64 k
    __shared__ ushort Bs[8 * 512];    // 64 rows x 64 k
    const int f = blockIdx.x;         // 0..511
    const int g = f >> 3;
    const int b = ((g & 3) << 3) | (f & 7);
    const int n = g >> 2;             // 0..15
    const int tid = threadIdx.x;
    const int w = tid >> 6, lane = tid & 63;
    const int l15 = lane & 15, q = lane >> 4;
    const int wm = w >> 1, wn = w & 1;
    const int n0 = n * 64;

    const int sr = lane >> 3;
    const int ssg = ((lane & 7) ^ sr) * 8;

    const ushort* Abase = py + (size_t)(b * SEQL + sr) * DMOD + ssg;
    const ushort* Bbase = xe + (size_t)(b * SRCN + n0 + sr) * DMOD + ssg;

    floatx4 acc[4][2];
    #pragma unroll
    for (int mi = 0; mi < 4; ++mi)
        #pragma unroll
        for (int ni = 0; ni < 2; ++ni)
            acc[mi][ni] = (floatx4){0.f, 0.f, 0.f, 0.f};

    for (int kk = 0; kk < DMOD; kk += 64) {
        __syncthreads();
        #pragma unroll
        for (int i = 0; i < 4; ++i) {
            const int cc = w * 4 + i;
            gload_lds16(Abase + (size_t)(cc * 8) * DMOD + kk, (void*)(As + cc * 512));
        }
        #pragma unroll
        for (int i = 0; i < 2; ++i) {
            const int cc = w * 2 + i;
            gload_lds16(Bbase + (size_t)(cc * 8) * DMOD + kk, (void*)(Bs + cc * 512));
        }
        __syncthreads();
        #pragma unroll
        for (int s2 = 0; s2 < 2; ++s2) {
            const int sg = s2 * 4 + q;
            short8 af[4], bf[2];
            #pragma unroll
            for (int mi = 0; mi < 4; ++mi)
                af[mi] = *(const short8*)(As + LSLOT(wm * 64 + mi * 16 + l15, sg));
            #pragma unroll
            for (int ni = 0; ni < 2; ++ni)
                bf[ni] = *(const short8*)(Bs + LSLOT(wn * 32 + ni * 16 + l15, sg));
            #pragma unroll
            for (int mi = 0; mi < 4; ++mi)
                #pragma unroll
                for (int ni = 0; ni < 2; ++ni)
                    acc[mi][ni] = __builtin_amdgcn_mfma_f32_16x16x32_bf16(
                        af[mi], bf[ni], acc[mi][ni], 0, 0, 0);
        }
    }

    #pragma unroll
    for (int ni = 0; ni < 2; ++ni) {
        const int col = n0 + wn * 32 + ni * 16 + l15;
        const float msk = (x[b * SRCN + col] == 0) ? -1e9f : 0.0f;
        #pragma unroll
        for (int mi = 0; mi < 4; ++mi) {
            const int row0 = wm * 64 + mi * 16 + q * 4;
            #pragma unroll
            for (int r = 0; r < 4; ++r)
                a_out[((size_t)b * SEQL + row0 + r) * SRCN + col] = acc[mi][ni][r] + msk;
        }
    }
}

// ---------------------------------------------------------------------------
// Row softmax over 1024 (mask already applied); fp32 in place + bf16 copy
// ---------------------------------------------------------------------------
__global__ __launch_bounds__(256) void k_softmax(
    float* __restrict__ a, ushort* __restrict__ abf)
{
    const int row = blockIdx.x;          // b*128+s
    float* p = a + (size_t)row * SRCN;
    ushort* pb = abf + (size_t)row * SRCN;
    const int tid = threadIdx.x;
    const int wave = tid >> 6, lane = tid & 63;

    float4 v = *(const float4*)(p + tid * 4);

    float mx = fmaxf(fmaxf(v.x, v.y), fmaxf(v.z, v.w));
    #pragma unroll
    for (int off = 32; off > 0; off >>= 1)
        mx = fmaxf(mx, __shfl_down(mx, off, 64));
    __shared__ float redm[4];
    if (lane == 0) redm[wave] = mx;
    __syncthreads();
    mx = fmaxf(fmaxf(redm[0], redm[1]), fmaxf(redm[2], redm[3]));

    const float e0 = __expf(v.x - mx);
    const float e1 = __expf(v.y - mx);
    const float e2 = __expf(v.z - mx);
    const float e3 = __expf(v.w - mx);

    float sm = e0 + e1 + e2 + e3;
    #pragma unroll
    for (int off = 32; off > 0; off >>= 1)
        sm += __shfl_down(sm, off, 64);
    __shared__ float reds[4];
    if (lane == 0) reds[wave] = sm;
    __syncthreads();
    sm = reds[0] + reds[1] + reds[2] + reds[3];

    const float inv = 1.0f / sm;
    float4 o;
    o.x = e0 * inv; o.y = e1 * inv; o.z = e2 * inv; o.w = e3 * inv;
    *(float4*)(p + tid * 4) = o;
    ushort4 ob;
    ob.x = f2b(o.x); ob.y = f2b(o.y); ob.z = f2b(o.z); ob.w = f2b(o.w);
    *(ushort4*)(pb + tid * 4) = ob;
}

// ---------------------------------------------------------------------------
// GEMM3: out[b][m0:m0+64][n0:n0+64] = abf_b @ xet_b^T (K=1024), fp32 out.
// Tile 64x64, BK=128 (two 64-k sub-chunks per barrier), 512 blocks.
// ---------------------------------------------------------------------------
__global__ __launch_bounds__(256) void k_gemm_out(
    const ushort* __restrict__ abf, const ushort* __restrict__ xet,
    float* __restrict__ outp)
{
    __shared__ ushort As[2 * 8 * 512];   // 2 sub-k x (64 rows x 64 k)
    __shared__ ushort Bs[2 * 8 * 512];
    const int f = blockIdx.x;            // 0..511
    const int g = f >> 3;
    const int b = ((g & 3) << 3) | (f & 7);
    const int h = g >> 2;                // 0..15
    const int m = h & 1, n = h >> 1;     // 2 m x 8 n
    const int tid = threadIdx.x;
    const int w = tid >> 6, lane = tid & 63;
    const int l15 = lane & 15, q = lane >> 4;
    const int wm = w >> 1, wn = w & 1;
    const int m0 = m * 64, n0 = n * 64;

    const int sr = lane >> 3;
    const int ssg = ((lane & 7) ^ sr) * 8;

    const ushort* Abase = abf + (size_t)(b * SEQL + m0 + sr) * SRCN + ssg;
    const ushort* Bbase = xet + (size_t)(b * DMOD + n0 + sr) * SRCN + ssg;

    floatx4 acc[2][2];
    #pragma unroll
    for (int mi = 0; mi < 2; ++mi)
        #pragma unroll
        for (int ni = 0; ni < 2; ++ni)
            acc[mi][ni] = (floatx4){0.f, 0.f, 0.f, 0.f};

    for (int kk = 0; kk < SRCN; kk += 128) {
        __syncthreads();
        #pragma unroll
        for (int sub = 0; sub < 2; ++sub) {
            #pragma unroll
            for (int i = 0; i < 2; ++i) {
                const int cc = w * 2 + i;
                gload_lds16(Abase + (size_t)(cc * 8) * SRCN + kk + sub * 64,
                            (void*)(As + sub * 4096 + cc * 512));
                gload_lds16(Bbase + (size_t)(cc * 8) * SRCN + kk + sub * 64,
                            (void*)(Bs + sub * 4096 + cc * 512));
            }
        }
        __syncthreads();
        #pragma unroll
        for (int sub = 0; sub < 2; ++sub) {
            #pragma unroll
            for (int s2 = 0; s2 < 2; ++s2) {
                const int sg = s2 * 4 + q;
                short8 af[2], bf[2];
                #pragma unroll
                for (int mi = 0; mi < 2; ++mi)
                    af[mi] = *(const short8*)(As + sub * 4096 + LSLOT(wm * 32 + mi * 16 + l15, sg));
                #pragma unroll
                for (int ni = 0; ni < 2; ++ni)
                    bf[ni] = *(const short8*)(Bs + sub * 4096 + LSLOT(wn * 32 + ni * 16 + l15, sg));
                #pragma unroll
                for (int mi = 0; mi < 2; ++mi)
                    #pragma unroll
                    for (int ni = 0; ni < 2; ++ni)
                        acc[mi][ni] = __builtin_amdgcn_mfma_f32_16x16x32_bf16(
                            af[mi], bf[ni], acc[mi][ni], 0, 0, 0);
            }
        }
    }

    #pragma unroll
    for (int ni = 0; ni < 2; ++ni) {
        const int col = n0 + wn * 32 + ni * 16 + l15;
        #pragma unroll
        for (int mi = 0; mi < 2; ++mi) {
            const int row0 = m0 + wm * 32 + mi * 16 + q * 4;
            #pragma unroll
            for (int r = 0; r < 4; ++r)
                outp[((size_t)b * SEQL + row0 + r) * DMOD + col] = acc[mi][ni][r];
        }
    }
}

// ---------------------------------------------------------------------------
extern "C" void kernel_launch(void* const* d_in, const int* in_sizes, int n_in,
                              void* d_out, int out_size, void* d_ws, size_t ws_size,
                              hipStream_t stream)
{
    const int*   x    = (const int*)d_in[0];    // [32,1024]
    const int*   yc   = (const int*)d_in[1];    // [32,640]
    const float* Femb = (const float*)d_in[2];  // [32000,512]
    const float* Gemb = (const float*)d_in[3];  // [32000,512]
    const float* Pw   = (const float*)d_in[4];  // [2560,512]
    const float* Pb   = (const float*)d_in[5];  // [512]

    float* out_p = (float*)d_out;                         // [32,128,512]
    float* a_p   = out_p + (size_t)BATCH * SEQL * DMOD;   // [32,128,1024]

    // Workspace with lifetime aliasing:
    //   yce  [0,        20971520)  live: prep .. gemm_py
    //   pwt  [20971520, 23592960)  live: prep .. gemm_py
    //   part [23592960, 57147392)  live: gemm_py .. red4   (4 x 8.39 MB fp32)
    //   xe   [0,        33554432)  live: xe2 .. gemm_sc    (after red4)
    //   xet  [33554432, 67108864)  live: xe2 .. gemm_out   (after red4)
    //   py   [67108864, 71303168)  live: red4 .. gemm_sc
    //   abf  [71303168, 79691776)  live: softmax .. gemm_out
    char* ws = (char*)d_ws;
    ushort* yce  = (ushort*)(ws);
    ushort* pwt  = (ushort*)(ws + 20971520);
    float*  part = (float*) (ws + 23592960);
    ushort* xe   = (ushort*)(ws);
    ushort* xet  = (ushort*)(ws + 33554432);
    ushort* py   = (ushort*)(ws + 67108864);
    ushort* abf  = (ushort*)(ws + 71303168);

    dim3 blk(256);
    k_prep<<<dim3(4416), blk, 0, stream>>>(yc, Gemb, yce, Pw, pwt);

    // GEMM1 split-K=4, 128x64 tiles: 1024 blocks (4/CU), XCD-swizzled
    k_gemm_py<<<dim3(1024), blk, 0, stream>>>(yce, pwt, part);
    k_red4<<<dim3(2048), blk, 0, stream>>>(part, Pb, py);

    // gather F -> xe + xet (after red4: may overwrite yce/pwt/part)
    k_xe2<<<dim3(16, 8, 32), blk, 0, stream>>>(x, Femb, xe, xet);

    // GEMM2 128x64 tiles: 512 blocks, mask fused
    k_gemm_sc<<<dim3(512), blk, 0, stream>>>(py, x, xe, a_p);
    k_softmax<<<dim3(4096), blk, 0, stream>>>(a_p, abf);
    // GEMM3 64x64 BK=128: 512 blocks
    k_gemm_out<<<dim3(512), blk, 0, stream>>>(abf, xet, out_p);
}